// Round 1
// baseline (1986.688 us; speedup 1.0000x reference)
//
#include <hip/hip_runtime.h>

typedef _Float16 f16;
typedef _Float16 f16x8 __attribute__((ext_vector_type(8)));
typedef float f32x4 __attribute__((ext_vector_type(4)));

#define BM 128
#define BN 128
#define BK 32

// async global->LDS, 16B per lane. LDS dest is wave-uniform base + lane*16;
// we pass the per-lane linear address (correct under both semantics).
__device__ __forceinline__ void gload_lds16(const void* g, void* l) {
  __builtin_amdgcn_global_load_lds(
      (const __attribute__((address_space(1))) void*)g,
      (__attribute__((address_space(3))) void*)l,
      16, 0, 0);
}

__device__ __forceinline__ float act_apply(float x, int id) {
  switch (id) {
    case 0: return fmaxf(x, 0.0f);
    case 1: return 1.0f / (1.0f + __expf(-x));   // large |x| saturates correctly
    case 2: return tanhf(x);
    case 3: return x >= 0.0f ? x : 0.1f * x;
    default: return 1.0507009873554805f *
                    (x > 0.0f ? x : 1.6732632423543772f * expm1f(x));
  }
}

// C = act(A @ W^T * Sa + bias) * invSn
// A: M x K (fp16, scaled by 1/Sa), W: N x K (fp16), out: M x N (fp16 or fp32)
template <bool FINAL>
__global__ __launch_bounds__(256, 2)
void gemm_bias_act(const f16* __restrict__ A, const f16* __restrict__ W,
                   const float* __restrict__ bias, const int* __restrict__ ids,
                   float Sa, float invSn, void* __restrict__ outv,
                   int M, int N, int K) {
  __shared__ f16 lA[BM * BK];
  __shared__ f16 lB[BN * BK];

  const int tid  = (int)threadIdx.x;
  const int lane = tid & 63;
  const int wid  = tid >> 6;
  const int wr   = (wid >> 1) * 64;   // wave row offset in tile
  const int wc   = (wid & 1) * 64;    // wave col offset in tile

  // bijective XCD-aware swizzle (nwg % 8 == 0 for all our shapes)
  const int nbx = N >> 7;
  const int nwg = (M >> 7) * nbx;
  const int b   = (int)blockIdx.x;
  const int swz = (b & 7) * (nwg >> 3) + (b >> 3);
  const int brow = (swz / nbx) << 7;
  const int bcol = (swz % nbx) << 7;

  // staging: thread t loads 16B = 8 f16; tile row = t>>2 (+64 for issue 1),
  // k-offset = (t&3)*8. Linear in [128][32] LDS layout at elem t*8.
  const int srow = tid >> 2;
  const int scol = (tid & 3) << 3;
  const f16* gA0 = A + (long)(brow + srow) * K + scol;
  const f16* gA1 = gA0 + (long)64 * K;
  const f16* gB0 = W + (long)(bcol + srow) * K + scol;
  const f16* gB1 = gB0 + (long)64 * K;

  f16* ldA0 = &lA[tid * 8];
  f16* ldA1 = &lA[2048 + tid * 8];
  f16* ldB0 = &lB[tid * 8];
  f16* ldB1 = &lB[2048 + tid * 8];

  // fragment addressing: A row / B col = lane&15, k0 = 8*(lane>>4)
  const int fr = lane & 15;
  const int k8 = (lane >> 4) << 3;

  f32x4 acc[4][4];
#pragma unroll
  for (int i = 0; i < 4; ++i)
#pragma unroll
    for (int j = 0; j < 4; ++j) acc[i][j] = (f32x4){0.f, 0.f, 0.f, 0.f};

  for (int kk = 0; kk < K; kk += BK) {
    gload_lds16(gA0 + kk, ldA0);
    gload_lds16(gA1 + kk, ldA1);
    gload_lds16(gB0 + kk, ldB0);
    gload_lds16(gB1 + kk, ldB1);
    __syncthreads();  // compiler drains vmcnt before s_barrier

    f16x8 af[4], bf[4];
#pragma unroll
    for (int m = 0; m < 4; ++m)
      af[m] = *(const f16x8*)&lA[(wr + m * 16 + fr) * BK + k8];
#pragma unroll
    for (int n = 0; n < 4; ++n)
      bf[n] = *(const f16x8*)&lB[(wc + n * 16 + fr) * BK + k8];

#pragma unroll
    for (int m = 0; m < 4; ++m)
#pragma unroll
      for (int n = 0; n < 4; ++n)
        acc[m][n] = __builtin_amdgcn_mfma_f32_16x16x32_f16(af[m], bf[n],
                                                           acc[m][n], 0, 0, 0);
    __syncthreads();
  }

  // D layout (m89-verified): row = (lane>>4)*4 + reg, col = lane&15
  const int r4 = (lane >> 4) << 2;
#pragma unroll
  for (int n = 0; n < 4; ++n) {
    const int gcol = bcol + wc + n * 16 + fr;
    const float bv = bias[gcol];
    const int id   = ids[gcol];
#pragma unroll
    for (int m = 0; m < 4; ++m) {
      const int grow = brow + wr + m * 16 + r4;
#pragma unroll
      for (int i = 0; i < 4; ++i) {
        const float y = act_apply(acc[m][n][i] * Sa + bv, id);
        if (FINAL) {
          ((float*)outv)[(long)(grow + i) * N + gcol] = y;
        } else {
          ((f16*)outv)[(long)(grow + i) * N + gcol] = (f16)(y * invSn);
        }
      }
    }
  }
}

__global__ void cvt_f32_to_f16(const float* __restrict__ in, f16* __restrict__ out,
                               float scale, int n) {
  int i = ((int)blockIdx.x * 256 + (int)threadIdx.x) * 8;
  const int stride = (int)gridDim.x * 256 * 8;
  for (; i < n; i += stride) {
    const float4 v0 = *(const float4*)(in + i);
    const float4 v1 = *(const float4*)(in + i + 4);
    f16x8 h;
    h[0] = (f16)(v0.x * scale); h[1] = (f16)(v0.y * scale);
    h[2] = (f16)(v0.z * scale); h[3] = (f16)(v0.w * scale);
    h[4] = (f16)(v1.x * scale); h[5] = (f16)(v1.y * scale);
    h[6] = (f16)(v1.z * scale); h[7] = (f16)(v1.w * scale);
    *(f16x8*)(out + i) = h;
  }
}

extern "C" void kernel_launch(void* const* d_in, const int* in_sizes, int n_in,
                              void* d_out, int out_size, void* d_ws, size_t ws_size,
                              hipStream_t stream) {
  (void)in_sizes; (void)n_in; (void)out_size; (void)ws_size;
  const int M = 8192, IND = 2048, HID = 4096, OUTD = 2048;
  const float* x = (const float*)d_in[0];

  // workspace: actA (8192*4096 f16) | actB (8192*4096 f16) | wbuf (4096*4096 f16)
  // total = 167,772,160 bytes
  f16* actA = (f16*)d_ws;
  f16* actB = actA + (size_t)M * HID;
  f16* wbuf = actB + (size_t)M * HID;

  // static per-layer activation scales (powers of 2, exact): h_i stored as h/S[i]
  const float S[6] = {1.f, 16.f, 512.f, 16384.f, 262144.f, 8388608.f};

  const int Ks[6] = {IND, HID, HID, HID, HID, HID};
  const int Ns[6] = {HID, HID, HID, HID, HID, OUTD};

  cvt_f32_to_f16<<<2048, 256, 0, stream>>>(x, actA, 1.0f, M * IND);

  f16* cur = actA;
  f16* nxt = actB;
  for (int i = 0; i < 6; ++i) {
    const int K = Ks[i], N = Ns[i];
    const float* w  = (const float*)d_in[1 + 3 * i];
    const float* bs = (const float*)d_in[2 + 3 * i];
    const int* id   = (const int*)d_in[3 + 3 * i];

    cvt_f32_to_f16<<<2048, 256, 0, stream>>>(w, wbuf, 1.0f, N * K);

    const int nblk = (M >> 7) * (N >> 7);
    if (i < 5) {
      gemm_bias_act<false><<<nblk, 256, 0, stream>>>(
          cur, wbuf, bs, id, S[i], 1.0f / S[i + 1], nxt, M, N, K);
      f16* t = cur; cur = nxt; nxt = t;
    } else {
      gemm_bias_act<true><<<nblk, 256, 0, stream>>>(
          cur, wbuf, bs, id, S[i], 1.0f, d_out, M, N, K);
    }
  }
}